// Round 26
// baseline (1036.714 us; speedup 1.0000x reference)
//
#include <hip/hip_runtime.h>
#include <hip/hip_bf16.h>
#include <hip/hip_fp16.h>

#define N_MOL 128
#define STRESS_FLOATS (N_MOL * 9)   // 1152
#define NB 128                      // buckets
#define APB 1563                    // atoms/bucket: 128*1563 >= 200000
#define NPAD (NB * APB)
#define EPB 1024                    // edges per scatter block
#define BLK_S 512                   // scatter block (r25: 84% occupancy)
#define K_PT 2                      // EPB / BLK_S
#define BLK 256
#define RS_SLICES 64

// ---------------------------------------------------------------------------
__global__ void zero_i32_kernel(int* __restrict__ p, int n) {
    int i = blockIdx.x * blockDim.x + threadIdx.x;
    if (i < n) p[i] = 0;
}

__device__ __forceinline__ unsigned short h16(float v) {
    return __half_as_ushort(__float2half_rn(v));
}

// ---------------------------------------------------------------------------
// Combined scatter+stress; reservations rounded to 8 records (64B) so every
// stream-out run is whole cache lines (kills the measured 1.46x write
// amplification). Pad slots written as zero-records (harmless in accum).
// ---------------------------------------------------------------------------
__global__ void __launch_bounds__(512)
scatter_kernel(const float* __restrict__ dEdRij,
               const float* __restrict__ Rij,
               const int*   __restrict__ idx_i,
               const int*   __restrict__ idx_j,
               const int*   __restrict__ idx_m,
               uint2* __restrict__ rec,     // [NB][CAP], CAP % 8 == 0
               int*   __restrict__ cnt,     // [NB] (this chunk's slice)
               float* __restrict__ spart,   // [ROWS][1152]
               int e0_chunk, int n_edges_chunk, int CAP, int sstore)
{
    __shared__ int           hist[NB];
    __shared__ int           excl[NB];
    __shared__ int           cur[NB];
    __shared__ int           shiftb[NB];
    __shared__ float         smem[STRESS_FLOATS];
    __shared__ uint2         stg[EPB * 2];      // 16 KB
    __shared__ unsigned char stgb[EPB * 2];     // 2 KB

    for (int t = threadIdx.x; t < NB; t += blockDim.x) hist[t] = 0;
    for (int t = threadIdx.x; t < STRESS_FLOATS; t += blockDim.x) smem[t] = 0.f;
    __syncthreads();

    const int be0 = e0_chunk + blockIdx.x * EPB;
    const int be1 = min(be0 + EPB, e0_chunk + n_edges_chunk);

    // ---- phase 1: idx loads into regs + LDS histogram
    int ei[K_PT], ej[K_PT];
    #pragma unroll
    for (int k = 0; k < K_PT; ++k) {
        const int e = be0 + k * BLK_S + threadIdx.x;
        ei[k] = -1; ej[k] = -1;
        if (e < be1) {
            ei[k] = idx_i[e];
            ej[k] = idx_j[e];
            atomicAdd(&hist[ei[k] / APB], 1);
            atomicAdd(&hist[ej[k] / APB], 1);
        }
    }
    __syncthreads();                       // histogram complete (r11 lesson)

    // ---- wave-0 exclusive scan over NB=128 (2 entries/lane, shfl)
    if (threadIdx.x < 64) {
        const int l = threadIdx.x;
        const int a = hist[2 * l], b = hist[2 * l + 1];
        int s = a + b;
        #pragma unroll
        for (int off = 1; off < 64; off <<= 1) {
            const int v = __shfl_up(s, off, 64);
            if (l >= off) s += v;
        }
        const int excl_pair = s - (a + b);
        excl[2 * l]     = excl_pair;
        excl[2 * l + 1] = excl_pair + a;
    }
    __syncthreads();

    // ---- reservation: rounded to 8-record (64B) units; pads zero-filled
    for (int t = threadIdx.x; t < NB; t += blockDim.x) {
        const int h    = hist[t];
        const int ex   = excl[t];
        const int hpad = (h + 7) & ~7;             // 64B-aligned run length
        const int g    = h ? atomicAdd(&cnt[t], hpad) : 0;
        cur[t]    = ex;
        shiftb[t] = t * CAP + g - ex;
        // zero-records in the pad tail (same cache lines as the run)
        const int lim = (t + 1) * CAP;
        for (int p = g + h; p < g + hpad; ++p) {
            const int gi = t * CAP + p;
            if (gi < lim) rec[gi] = make_uint2(0u, 0u);
        }
    }
    __syncthreads();

    // ---- phase 2: float loads, stress accum, 8B bucket-major staging
    #pragma unroll
    for (int k = 0; k < K_PT; ++k) {
        const int e = be0 + k * BLK_S + threadIdx.x;
        if (e >= be1) continue;
        const int i = ei[k], j = ej[k];
        const float dx = dEdRij[3*e+0], dy = dEdRij[3*e+1], dz = dEdRij[3*e+2];
        const float rx = Rij[3*e+0],    ry = Rij[3*e+1],    rz = Rij[3*e+2];

        const int m = idx_m[i];
        float* s = &smem[m * 9];
        atomicAdd(&s[0], rx * dx);
        atomicAdd(&s[1], rx * dy);
        atomicAdd(&s[2], rx * dz);
        atomicAdd(&s[3], ry * dx);
        atomicAdd(&s[4], ry * dy);
        atomicAdd(&s[5], ry * dz);
        atomicAdd(&s[6], rz * dx);
        atomicAdd(&s[7], rz * dy);
        atomicAdd(&s[8], rz * dz);

        const int bi = i / APB;
        const int li = i - bi * APB;
        uint2 q;
        q.x = ((unsigned)li << 16) | h16(dx);
        q.y = (unsigned)h16(dy) | ((unsigned)h16(dz) << 16);
        int p = atomicAdd(&cur[bi], 1);
        stg[p] = q; stgb[p] = (unsigned char)bi;

        const int bj = j / APB;
        const int lj = j - bj * APB;
        q.x = ((unsigned)lj << 16) | h16(-dx);
        q.y = (unsigned)h16(-dy) | ((unsigned)h16(-dz) << 16);
        p = atomicAdd(&cur[bj], 1);
        stg[p] = q; stgb[p] = (unsigned char)bj;
    }
    __syncthreads();

    // ---- stream-out: 64B-aligned bucket-major runs -> full-line writes
    const int total = 2 * (be1 - be0);
    for (int t = threadIdx.x; t < total; t += blockDim.x) {
        const int b = stgb[t];
        const int gidx = t + shiftb[b];
        if (gidx < (b + 1) * CAP)          // capacity guard (drop-only)
            rec[gidx] = stg[t];
    }

    __syncthreads();
    float* sp = spart + (size_t)blockIdx.x * STRESS_FLOATS;
    if (sstore) {
        for (int t = threadIdx.x; t < STRESS_FLOATS; t += blockDim.x)
            sp[t] = smem[t];
    } else {
        for (int t = threadIdx.x; t < STRESS_FLOATS; t += blockDim.x)
            sp[t] += smem[t];
    }
}

// ---------------------------------------------------------------------------
// Pass D: S blocks per bucket. uint4 paired loads, 8-deep unroll.
// store=1 on chunk 0. Pad records add 0.0 to atom 0 — harmless.
// ---------------------------------------------------------------------------
__global__ void __launch_bounds__(256)
accum_kernel(const uint2* __restrict__ rec,
             const int*   __restrict__ cnt,
             float* __restrict__ partial,   // [S][NPAD*3]
             int CAP, int S, int store)
{
    __shared__ float facc[APB * 3];        // 18.8 KB
    const int b = blockIdx.x / S;
    const int s = blockIdx.x - b * S;
    for (int t = threadIdx.x; t < APB * 3; t += blockDim.x) facc[t] = 0.f;
    __syncthreads();

    int n = cnt[b];
    if (n > CAP) n = CAP;
    int r0 = (int)((long long)n * s / S);
    int r1 = (int)((long long)n * (s + 1) / S);
    const uint2* rb = rec + (size_t)b * CAP;

#define ACC1(w0, w1)                                                  \
    {                                                                 \
        const int   l  = (int)((w0) >> 16);                           \
        const float fx = __half2float(__ushort_as_half(               \
                             (unsigned short)((w0) & 0xffffu)));      \
        const float fy = __half2float(__ushort_as_half(               \
                             (unsigned short)((w1) & 0xffffu)));      \
        const float fz = __half2float(__ushort_as_half(               \
                             (unsigned short)((w1) >> 16)));          \
        atomicAdd(&facc[l * 3 + 0], fx);                              \
        atomicAdd(&facc[l * 3 + 1], fy);                              \
        atomicAdd(&facc[l * 3 + 2], fz);                              \
    }

    if (r0 < r1 && (r0 & 1)) {
        if (threadIdx.x == 0) { const uint2 q = rb[r0]; ACC1(q.x, q.y); }
        ++r0;
    }
    if (r0 < r1 && (r1 & 1)) {
        --r1;
        if (threadIdx.x == 0) { const uint2 q = rb[r1]; ACC1(q.x, q.y); }
    }
    const int npair = (r1 - r0) >> 1;
    const uint4* rp = (const uint4*)(rb + r0);

    int p = threadIdx.x;
    for (; p + 7 * BLK < npair; p += 8 * BLK) {
        uint4 q0 = rp[p];
        uint4 q1 = rp[p + 1 * BLK];
        uint4 q2 = rp[p + 2 * BLK];
        uint4 q3 = rp[p + 3 * BLK];
        uint4 q4 = rp[p + 4 * BLK];
        uint4 q5 = rp[p + 5 * BLK];
        uint4 q6 = rp[p + 6 * BLK];
        uint4 q7 = rp[p + 7 * BLK];
        ACC1(q0.x, q0.y); ACC1(q0.z, q0.w);
        ACC1(q1.x, q1.y); ACC1(q1.z, q1.w);
        ACC1(q2.x, q2.y); ACC1(q2.z, q2.w);
        ACC1(q3.x, q3.y); ACC1(q3.z, q3.w);
        ACC1(q4.x, q4.y); ACC1(q4.z, q4.w);
        ACC1(q5.x, q5.y); ACC1(q5.z, q5.w);
        ACC1(q6.x, q6.y); ACC1(q6.z, q6.w);
        ACC1(q7.x, q7.y); ACC1(q7.z, q7.w);
    }
    for (; p < npair; p += BLK) {
        const uint4 q = rp[p];
        ACC1(q.x, q.y); ACC1(q.z, q.w);
    }
#undef ACC1

    __syncthreads();
    float* pp = partial + ((size_t)s * NPAD + (size_t)b * APB) * 3;
    if (store) {
        for (int t = threadIdx.x; t < APB * 3; t += blockDim.x)
            pp[t] = facc[t];
    } else {
        for (int t = threadIdx.x; t < APB * 3; t += blockDim.x)
            pp[t] += facc[t];
    }
}

// ---------------------------------------------------------------------------
__global__ void final_forces_kernel(const float* __restrict__ partial,
                                    float* __restrict__ forces, int n3, int S)
{
    const int t = blockIdx.x * blockDim.x + threadIdx.x;
    if (t >= n3) return;
    float a = 0.f;
    for (int s = 0; s < S; ++s)
        a += partial[(size_t)s * NPAD * 3 + t];
    forces[t] = a;
}

// ---------------------------------------------------------------------------
__global__ void reduce_stress_stage1(const float* __restrict__ spart,
                                     float* __restrict__ stmp, int rows)
{
    const int t = blockIdx.x * blockDim.x + threadIdx.x;
    if (t >= STRESS_FLOATS * RS_SLICES) return;
    const int col = t % STRESS_FLOATS;
    const int sl  = t / STRESS_FLOATS;
    float acc = 0.f;
    for (int r = sl; r < rows; r += RS_SLICES)
        acc += spart[(size_t)r * STRESS_FLOATS + col];
    stmp[sl * STRESS_FLOATS + col] = acc;
}

__global__ void reduce_stress_stage2(const float* __restrict__ stmp,
                                     const float* __restrict__ cell,
                                     float* __restrict__ out_stress)
{
    const int t = blockIdx.x * blockDim.x + threadIdx.x;
    if (t >= STRESS_FLOATS) return;
    float acc = 0.f;
    for (int s = 0; s < RS_SLICES; ++s)
        acc += stmp[s * STRESS_FLOATS + t];
    const int m = t / 9;
    const float* c = &cell[m * 9];
    const float a0 = c[0], a1 = c[1], a2 = c[2];
    const float b0 = c[3], b1 = c[4], b2 = c[5];
    const float c0 = c[6], c1 = c[7], c2 = c[8];
    const float x0 = b1 * c2 - b2 * c1;
    const float x1 = b2 * c0 - b0 * c2;
    const float x2 = b0 * c1 - b1 * c0;
    const float vol = a0 * x0 + a1 * x1 + a2 * x2;
    out_stress[t] = acc / vol;
}

// ===========================================================================
// Fallback: round-6 measured f64 atomic path (known passing)
// ===========================================================================
__global__ void zero_f64_kernel(double* __restrict__ p, int n) {
    int i = blockIdx.x * blockDim.x + threadIdx.x;
    if (i < n) p[i] = 0.0;
}

__global__ void __launch_bounds__(256)
edge_kernel_f64(const float* __restrict__ dEdRij,
                const float* __restrict__ Rij,
                const int*   __restrict__ idx_i,
                const int*   __restrict__ idx_j,
                const int*   __restrict__ idx_m,
                double* __restrict__ facc,
                float*  __restrict__ spart,
                int E)
{
    __shared__ float smem[STRESS_FLOATS];
    for (int t = threadIdx.x; t < STRESS_FLOATS; t += blockDim.x) smem[t] = 0.f;
    __syncthreads();
    const int stride = gridDim.x * blockDim.x;
    for (int e = blockIdx.x * blockDim.x + threadIdx.x; e < E; e += stride) {
        const int i = idx_i[e], j = idx_j[e];
        const float dx = dEdRij[3*e+0], dy = dEdRij[3*e+1], dz = dEdRij[3*e+2];
        const float rx = Rij[3*e+0],    ry = Rij[3*e+1],    rz = Rij[3*e+2];
        double* fi = facc + 3 * (size_t)i;
        unsafeAtomicAdd(fi + 0, (double) dx);
        unsafeAtomicAdd(fi + 1, (double) dy);
        unsafeAtomicAdd(fi + 2, (double) dz);
        double* fj = facc + 3 * (size_t)j;
        unsafeAtomicAdd(fj + 0, (double)-dx);
        unsafeAtomicAdd(fj + 1, (double)-dy);
        unsafeAtomicAdd(fj + 2, (double)-dz);
        const int m = idx_m[i];
        float* s = &smem[m * 9];
        atomicAdd(&s[0], rx*dx); atomicAdd(&s[1], rx*dy); atomicAdd(&s[2], rx*dz);
        atomicAdd(&s[3], ry*dx); atomicAdd(&s[4], ry*dy); atomicAdd(&s[5], ry*dz);
        atomicAdd(&s[6], rz*dx); atomicAdd(&s[7], rz*dy); atomicAdd(&s[8], rz*dz);
    }
    __syncthreads();
    float* sp = spart + (size_t)blockIdx.x * STRESS_FLOATS;
    for (int t = threadIdx.x; t < STRESS_FLOATS; t += blockDim.x) sp[t] = smem[t];
}

__global__ void reduce_forces_f64_kernel(const double* __restrict__ facc,
                                         float* __restrict__ forces, int n3)
{
    int t = blockIdx.x * blockDim.x + threadIdx.x;
    if (t < n3) forces[t] = (float)facc[t];
}

// ===========================================================================
extern "C" void kernel_launch(void* const* d_in, const int* in_sizes, int n_in,
                              void* d_out, int out_size, void* d_ws, size_t ws_size,
                              hipStream_t stream)
{
    const float* dEdRij = (const float*)d_in[0];
    const float* Rij    = (const float*)d_in[1];
    const float* R      = (const float*)d_in[2];  (void)R;
    const float* cell   = (const float*)d_in[3];
    const int*   idx_i  = (const int*)d_in[4];
    const int*   idx_j  = (const int*)d_in[5];
    const int*   idx_m  = (const int*)d_in[6];

    const int E  = in_sizes[0] / 3;   // 10,000,000
    const int N  = in_sizes[2] / 3;   // 200,000
    const int n3 = N * 3;

    float* out        = (float*)d_out;
    float* forces     = out;
    float* stress_out = out + (size_t)n3;

    // ---- (nc, S) priority search.
    // CAP: mean + mean/4 (pad growth ~22% worst case) + 128, rounded to 8.
    int nchunks = 0, SEG = 0, CAP = 0, ROWS = 0;
    size_t rec_u2 = 0, spart_f = 0;
    {
        const int cand[13][2] = {
            {2,16},{2,8},{3,16},{3,8},{4,16},{4,8},{5,8},{2,4},
            {8,8},{8,4},{16,4},{20,2},{40,1}};
        for (int ci = 0; ci < 13; ++ci) {
            const int nc = cand[ci][0];
            const int S  = cand[ci][1];
            const int CH = (E + nc - 1) / nc;
            const long long mean = 2LL * CH / NB;
            int cap = (int)(mean + mean / 4 + 128);
            cap = (cap + 7) & ~7;                    // 64B-aligned bucket size
            const int rows = (CH + EPB - 1) / EPB;
            const size_t need = (size_t)NB * cap * sizeof(uint2)
                              + (size_t)rows * STRESS_FLOATS * sizeof(float)
                              + (size_t)nc * NB * sizeof(int)
                              + (size_t)RS_SLICES * STRESS_FLOATS * sizeof(float)
                              + (size_t)S * NPAD * 3 * sizeof(float)
                              + 256;
            if (need <= ws_size) {
                nchunks = nc; SEG = S; CAP = cap; ROWS = rows;
                rec_u2  = (size_t)NB * cap;
                spart_f = (size_t)rows * STRESS_FLOATS;
                break;
            }
        }
    }

    if (nchunks > 0) {
        uint2* rec   = (uint2*)d_ws;
        float* spart = (float*)(rec + rec_u2);
        int*   cnt   = (int*)(spart + spart_f);               // [nc][NB]
        float* stmp  = (float*)(cnt + (size_t)nchunks * NB);  // [64][1152]
        float* part  = stmp + (size_t)RS_SLICES * STRESS_FLOATS; // [S][NPAD*3]

        zero_i32_kernel<<<(nchunks * NB + BLK - 1) / BLK, BLK, 0, stream>>>(
            cnt, nchunks * NB);

        const int CH = (E + nchunks - 1) / nchunks;
        int chunk = 0;
        for (int s = 0; s < E; s += CH, ++chunk) {
            const int ce = min(CH, E - s);
            const int nb = (ce + EPB - 1) / EPB;

            scatter_kernel<<<nb, BLK_S, 0, stream>>>(
                dEdRij, Rij, idx_i, idx_j, idx_m,
                rec, cnt + (size_t)chunk * NB, spart, s, ce, CAP,
                chunk == 0 ? 1 : 0);

            accum_kernel<<<NB * SEG, BLK, 0, stream>>>(
                rec, cnt + (size_t)chunk * NB, part, CAP, SEG,
                chunk == 0 ? 1 : 0);
        }

        final_forces_kernel<<<(n3 + BLK - 1) / BLK, BLK, 0, stream>>>(
            part, forces, n3, SEG);
        reduce_stress_stage1<<<(STRESS_FLOATS * RS_SLICES + BLK - 1) / BLK,
                               BLK, 0, stream>>>(spart, stmp, ROWS);
        reduce_stress_stage2<<<(STRESS_FLOATS + BLK - 1) / BLK, BLK, 0, stream>>>(
            stmp, cell, stress_out);
    } else {
        // fallback: measured f64 atomic path
        double* facc   = (double*)d_ws;
        float*  spartf = (float*)(facc + n3);

        zero_f64_kernel<<<(n3 + BLK - 1) / BLK, BLK, 0, stream>>>(facc, n3);
        edge_kernel_f64<<<2048, BLK, 0, stream>>>(
            dEdRij, Rij, idx_i, idx_j, idx_m, facc, spartf, E);
        reduce_forces_f64_kernel<<<(n3 + BLK - 1) / BLK, BLK, 0, stream>>>(
            facc, forces, n3);
        reduce_stress_stage1<<<(STRESS_FLOATS * RS_SLICES + BLK - 1) / BLK,
                               BLK, 0, stream>>>(
            spartf, (float*)(spartf + (size_t)2048 * STRESS_FLOATS), 2048);
        reduce_stress_stage2<<<(STRESS_FLOATS + BLK - 1) / BLK, BLK, 0, stream>>>(
            (float*)(spartf + (size_t)2048 * STRESS_FLOATS), cell, stress_out);
    }
}

// Round 27
// 945.261 us; speedup vs baseline: 1.0967x; 1.0967x over previous
//
#include <hip/hip_runtime.h>
#include <hip/hip_bf16.h>
#include <hip/hip_fp16.h>

#define N_MOL 128
#define STRESS_FLOATS (N_MOL * 9)   // 1152
#define NB 128                      // buckets
#define APB 1563                    // atoms/bucket: 128*1563 >= 200000
#define NPAD (NB * APB)
#define EPB 1024                    // edges per scatter block
#define BLK_S 512                   // scatter block (r25: 84% occupancy, best)
#define K_PT 2                      // EPB / BLK_S
#define BLK 256
#define RS_SLICES 64

// ---------------------------------------------------------------------------
__global__ void zero_i32_kernel(int* __restrict__ p, int n) {
    int i = blockIdx.x * blockDim.x + threadIdx.x;
    if (i < n) p[i] = 0;
}

__device__ __forceinline__ unsigned short h16(float v) {
    return __half_as_ushort(__float2half_rn(v));
}

// ---------------------------------------------------------------------------
// Combined scatter+stress (r25 configuration — best measured: 946 us total).
// histogram -> wave0 shfl scan -> reservation -> bucket-major 8B records ->
// coalesced stream-out; stress LDS accum -> spart[blk] (store chunk0, += after).
// ---------------------------------------------------------------------------
__global__ void __launch_bounds__(512)
scatter_kernel(const float* __restrict__ dEdRij,
               const float* __restrict__ Rij,
               const int*   __restrict__ idx_i,
               const int*   __restrict__ idx_j,
               const int*   __restrict__ idx_m,
               uint2* __restrict__ rec,     // [NB][CAP]
               int*   __restrict__ cnt,     // [NB] (this chunk's slice)
               float* __restrict__ spart,   // [ROWS][1152]
               int e0_chunk, int n_edges_chunk, int CAP, int sstore)
{
    __shared__ int           hist[NB];
    __shared__ int           excl[NB];
    __shared__ int           cur[NB];
    __shared__ int           shiftb[NB];
    __shared__ float         smem[STRESS_FLOATS];
    __shared__ uint2         stg[EPB * 2];      // 16 KB
    __shared__ unsigned char stgb[EPB * 2];     // 2 KB

    for (int t = threadIdx.x; t < NB; t += blockDim.x) hist[t] = 0;
    for (int t = threadIdx.x; t < STRESS_FLOATS; t += blockDim.x) smem[t] = 0.f;
    __syncthreads();

    const int be0 = e0_chunk + blockIdx.x * EPB;
    const int be1 = min(be0 + EPB, e0_chunk + n_edges_chunk);

    // ---- phase 1: idx loads into regs + LDS histogram
    int ei[K_PT], ej[K_PT];
    #pragma unroll
    for (int k = 0; k < K_PT; ++k) {
        const int e = be0 + k * BLK_S + threadIdx.x;
        ei[k] = -1; ej[k] = -1;
        if (e < be1) {
            ei[k] = idx_i[e];
            ej[k] = idx_j[e];
            atomicAdd(&hist[ei[k] / APB], 1);
            atomicAdd(&hist[ej[k] / APB], 1);
        }
    }
    __syncthreads();                       // histogram complete (r11 lesson)

    // ---- wave-0 exclusive scan over NB=128 (2 entries/lane, shfl)
    if (threadIdx.x < 64) {
        const int l = threadIdx.x;
        const int a = hist[2 * l], b = hist[2 * l + 1];
        int s = a + b;
        #pragma unroll
        for (int off = 1; off < 64; off <<= 1) {
            const int v = __shfl_up(s, off, 64);
            if (l >= off) s += v;
        }
        const int excl_pair = s - (a + b);
        excl[2 * l]     = excl_pair;
        excl[2 * l + 1] = excl_pair + a;
    }
    __syncthreads();

    // ---- reservation: one global atomic per non-empty bucket
    for (int t = threadIdx.x; t < NB; t += blockDim.x) {
        const int h  = hist[t];
        const int ex = excl[t];
        const int g  = h ? atomicAdd(&cnt[t], h) : 0;
        cur[t]    = ex;
        shiftb[t] = t * CAP + g - ex;
    }
    __syncthreads();

    // ---- phase 2: float loads, stress accum, 8B bucket-major staging
    #pragma unroll
    for (int k = 0; k < K_PT; ++k) {
        const int e = be0 + k * BLK_S + threadIdx.x;
        if (e >= be1) continue;
        const int i = ei[k], j = ej[k];
        const float dx = dEdRij[3*e+0], dy = dEdRij[3*e+1], dz = dEdRij[3*e+2];
        const float rx = Rij[3*e+0],    ry = Rij[3*e+1],    rz = Rij[3*e+2];

        const int m = idx_m[i];
        float* s = &smem[m * 9];
        atomicAdd(&s[0], rx * dx);
        atomicAdd(&s[1], rx * dy);
        atomicAdd(&s[2], rx * dz);
        atomicAdd(&s[3], ry * dx);
        atomicAdd(&s[4], ry * dy);
        atomicAdd(&s[5], ry * dz);
        atomicAdd(&s[6], rz * dx);
        atomicAdd(&s[7], rz * dy);
        atomicAdd(&s[8], rz * dz);

        const int bi = i / APB;
        const int li = i - bi * APB;
        uint2 q;
        q.x = ((unsigned)li << 16) | h16(dx);
        q.y = (unsigned)h16(dy) | ((unsigned)h16(dz) << 16);
        int p = atomicAdd(&cur[bi], 1);
        stg[p] = q; stgb[p] = (unsigned char)bi;

        const int bj = j / APB;
        const int lj = j - bj * APB;
        q.x = ((unsigned)lj << 16) | h16(-dx);
        q.y = (unsigned)h16(-dy) | ((unsigned)h16(-dz) << 16);
        p = atomicAdd(&cur[bj], 1);
        stg[p] = q; stgb[p] = (unsigned char)bj;
    }
    __syncthreads();

    // ---- stream-out: bucket-major runs -> coalesced
    const int total = 2 * (be1 - be0);
    for (int t = threadIdx.x; t < total; t += blockDim.x) {
        const int b = stgb[t];
        const int gidx = t + shiftb[b];
        if (gidx < (b + 1) * CAP)          // capacity guard (drop-only)
            rec[gidx] = stg[t];
    }

    __syncthreads();
    float* sp = spart + (size_t)blockIdx.x * STRESS_FLOATS;
    if (sstore) {
        for (int t = threadIdx.x; t < STRESS_FLOATS; t += blockDim.x)
            sp[t] = smem[t];
    } else {
        for (int t = threadIdx.x; t < STRESS_FLOATS; t += blockDim.x)
            sp[t] += smem[t];
    }
}

// ---------------------------------------------------------------------------
// Pass D: S blocks per bucket. uint4 paired loads, 8-deep unroll.
// store=1 on chunk 0 (no pre-zero, no RMW read).
// ---------------------------------------------------------------------------
__global__ void __launch_bounds__(256)
accum_kernel(const uint2* __restrict__ rec,
             const int*   __restrict__ cnt,
             float* __restrict__ partial,   // [S][NPAD*3]
             int CAP, int S, int store)
{
    __shared__ float facc[APB * 3];        // 18.8 KB
    const int b = blockIdx.x / S;
    const int s = blockIdx.x - b * S;
    for (int t = threadIdx.x; t < APB * 3; t += blockDim.x) facc[t] = 0.f;
    __syncthreads();

    int n = cnt[b];
    if (n > CAP) n = CAP;
    int r0 = (int)((long long)n * s / S);
    int r1 = (int)((long long)n * (s + 1) / S);
    const uint2* rb = rec + (size_t)b * CAP;

#define ACC1(w0, w1)                                                  \
    {                                                                 \
        const int   l  = (int)((w0) >> 16);                           \
        const float fx = __half2float(__ushort_as_half(               \
                             (unsigned short)((w0) & 0xffffu)));      \
        const float fy = __half2float(__ushort_as_half(               \
                             (unsigned short)((w1) & 0xffffu)));      \
        const float fz = __half2float(__ushort_as_half(               \
                             (unsigned short)((w1) >> 16)));          \
        atomicAdd(&facc[l * 3 + 0], fx);                              \
        atomicAdd(&facc[l * 3 + 1], fy);                              \
        atomicAdd(&facc[l * 3 + 2], fz);                              \
    }

    if (r0 < r1 && (r0 & 1)) {
        if (threadIdx.x == 0) { const uint2 q = rb[r0]; ACC1(q.x, q.y); }
        ++r0;
    }
    if (r0 < r1 && (r1 & 1)) {
        --r1;
        if (threadIdx.x == 0) { const uint2 q = rb[r1]; ACC1(q.x, q.y); }
    }
    const int npair = (r1 - r0) >> 1;
    const uint4* rp = (const uint4*)(rb + r0);

    int p = threadIdx.x;
    for (; p + 7 * BLK < npair; p += 8 * BLK) {
        uint4 q0 = rp[p];
        uint4 q1 = rp[p + 1 * BLK];
        uint4 q2 = rp[p + 2 * BLK];
        uint4 q3 = rp[p + 3 * BLK];
        uint4 q4 = rp[p + 4 * BLK];
        uint4 q5 = rp[p + 5 * BLK];
        uint4 q6 = rp[p + 6 * BLK];
        uint4 q7 = rp[p + 7 * BLK];
        ACC1(q0.x, q0.y); ACC1(q0.z, q0.w);
        ACC1(q1.x, q1.y); ACC1(q1.z, q1.w);
        ACC1(q2.x, q2.y); ACC1(q2.z, q2.w);
        ACC1(q3.x, q3.y); ACC1(q3.z, q3.w);
        ACC1(q4.x, q4.y); ACC1(q4.z, q4.w);
        ACC1(q5.x, q5.y); ACC1(q5.z, q5.w);
        ACC1(q6.x, q6.y); ACC1(q6.z, q6.w);
        ACC1(q7.x, q7.y); ACC1(q7.z, q7.w);
    }
    for (; p < npair; p += BLK) {
        const uint4 q = rp[p];
        ACC1(q.x, q.y); ACC1(q.z, q.w);
    }
#undef ACC1

    __syncthreads();
    float* pp = partial + ((size_t)s * NPAD + (size_t)b * APB) * 3;
    if (store) {
        for (int t = threadIdx.x; t < APB * 3; t += blockDim.x)
            pp[t] = facc[t];
    } else {
        for (int t = threadIdx.x; t < APB * 3; t += blockDim.x)
            pp[t] += facc[t];
    }
}

// ---------------------------------------------------------------------------
__global__ void final_forces_kernel(const float* __restrict__ partial,
                                    float* __restrict__ forces, int n3, int S)
{
    const int t = blockIdx.x * blockDim.x + threadIdx.x;
    if (t >= n3) return;
    float a = 0.f;
    for (int s = 0; s < S; ++s)
        a += partial[(size_t)s * NPAD * 3 + t];
    forces[t] = a;
}

// ---------------------------------------------------------------------------
__global__ void reduce_stress_stage1(const float* __restrict__ spart,
                                     float* __restrict__ stmp, int rows)
{
    const int t = blockIdx.x * blockDim.x + threadIdx.x;
    if (t >= STRESS_FLOATS * RS_SLICES) return;
    const int col = t % STRESS_FLOATS;
    const int sl  = t / STRESS_FLOATS;
    float acc = 0.f;
    for (int r = sl; r < rows; r += RS_SLICES)
        acc += spart[(size_t)r * STRESS_FLOATS + col];
    stmp[sl * STRESS_FLOATS + col] = acc;
}

__global__ void reduce_stress_stage2(const float* __restrict__ stmp,
                                     const float* __restrict__ cell,
                                     float* __restrict__ out_stress)
{
    const int t = blockIdx.x * blockDim.x + threadIdx.x;
    if (t >= STRESS_FLOATS) return;
    float acc = 0.f;
    for (int s = 0; s < RS_SLICES; ++s)
        acc += stmp[s * STRESS_FLOATS + t];
    const int m = t / 9;
    const float* c = &cell[m * 9];
    const float a0 = c[0], a1 = c[1], a2 = c[2];
    const float b0 = c[3], b1 = c[4], b2 = c[5];
    const float c0 = c[6], c1 = c[7], c2 = c[8];
    const float x0 = b1 * c2 - b2 * c1;
    const float x1 = b2 * c0 - b0 * c2;
    const float x2 = b0 * c1 - b1 * c0;
    const float vol = a0 * x0 + a1 * x1 + a2 * x2;
    out_stress[t] = acc / vol;
}

// ===========================================================================
// Fallback: round-6 measured f64 atomic path (known passing)
// ===========================================================================
__global__ void zero_f64_kernel(double* __restrict__ p, int n) {
    int i = blockIdx.x * blockDim.x + threadIdx.x;
    if (i < n) p[i] = 0.0;
}

__global__ void __launch_bounds__(256)
edge_kernel_f64(const float* __restrict__ dEdRij,
                const float* __restrict__ Rij,
                const int*   __restrict__ idx_i,
                const int*   __restrict__ idx_j,
                const int*   __restrict__ idx_m,
                double* __restrict__ facc,
                float*  __restrict__ spart,
                int E)
{
    __shared__ float smem[STRESS_FLOATS];
    for (int t = threadIdx.x; t < STRESS_FLOATS; t += blockDim.x) smem[t] = 0.f;
    __syncthreads();
    const int stride = gridDim.x * blockDim.x;
    for (int e = blockIdx.x * blockDim.x + threadIdx.x; e < E; e += stride) {
        const int i = idx_i[e], j = idx_j[e];
        const float dx = dEdRij[3*e+0], dy = dEdRij[3*e+1], dz = dEdRij[3*e+2];
        const float rx = Rij[3*e+0],    ry = Rij[3*e+1],    rz = Rij[3*e+2];
        double* fi = facc + 3 * (size_t)i;
        unsafeAtomicAdd(fi + 0, (double) dx);
        unsafeAtomicAdd(fi + 1, (double) dy);
        unsafeAtomicAdd(fi + 2, (double) dz);
        double* fj = facc + 3 * (size_t)j;
        unsafeAtomicAdd(fj + 0, (double)-dx);
        unsafeAtomicAdd(fj + 1, (double)-dy);
        unsafeAtomicAdd(fj + 2, (double)-dz);
        const int m = idx_m[i];
        float* s = &smem[m * 9];
        atomicAdd(&s[0], rx*dx); atomicAdd(&s[1], rx*dy); atomicAdd(&s[2], rx*dz);
        atomicAdd(&s[3], ry*dx); atomicAdd(&s[4], ry*dy); atomicAdd(&s[5], ry*dz);
        atomicAdd(&s[6], rz*dx); atomicAdd(&s[7], rz*dy); atomicAdd(&s[8], rz*dz);
    }
    __syncthreads();
    float* sp = spart + (size_t)blockIdx.x * STRESS_FLOATS;
    for (int t = threadIdx.x; t < STRESS_FLOATS; t += blockDim.x) sp[t] = smem[t];
}

__global__ void reduce_forces_f64_kernel(const double* __restrict__ facc,
                                         float* __restrict__ forces, int n3)
{
    int t = blockIdx.x * blockDim.x + threadIdx.x;
    if (t < n3) forces[t] = (float)facc[t];
}

// ===========================================================================
extern "C" void kernel_launch(void* const* d_in, const int* in_sizes, int n_in,
                              void* d_out, int out_size, void* d_ws, size_t ws_size,
                              hipStream_t stream)
{
    const float* dEdRij = (const float*)d_in[0];
    const float* Rij    = (const float*)d_in[1];
    const float* R      = (const float*)d_in[2];  (void)R;
    const float* cell   = (const float*)d_in[3];
    const int*   idx_i  = (const int*)d_in[4];
    const int*   idx_j  = (const int*)d_in[5];
    const int*   idx_m  = (const int*)d_in[6];

    const int E  = in_sizes[0] / 3;   // 10,000,000
    const int N  = in_sizes[2] / 3;   // 200,000
    const int n3 = N * 3;

    float* out        = (float*)d_out;
    float* forces     = out;
    float* stress_out = out + (size_t)n3;

    // ---- (nc, S) priority search (r25-proven config lands {2,16} or {2,8})
    int nchunks = 0, SEG = 0, CAP = 0, ROWS = 0;
    size_t rec_u2 = 0, spart_f = 0;
    {
        const int cand[13][2] = {
            {2,16},{3,16},{2,8},{3,8},{4,16},{4,8},{5,8},{2,4},
            {8,8},{8,4},{16,4},{20,2},{40,1}};
        for (int ci = 0; ci < 13; ++ci) {
            const int nc = cand[ci][0];
            const int S  = cand[ci][1];
            const int CH = (E + nc - 1) / nc;
            const long long mean = 2LL * CH / NB;
            int cap = (int)(mean + mean / 16 + 64);  // ~17+ sigma headroom
            cap = (cap + 1) & ~1;                    // even: 16B pair alignment
            const int rows = (CH + EPB - 1) / EPB;
            const size_t need = (size_t)NB * cap * sizeof(uint2)
                              + (size_t)rows * STRESS_FLOATS * sizeof(float)
                              + (size_t)nc * NB * sizeof(int)
                              + (size_t)RS_SLICES * STRESS_FLOATS * sizeof(float)
                              + (size_t)S * NPAD * 3 * sizeof(float)
                              + 256;
            if (need <= ws_size) {
                nchunks = nc; SEG = S; CAP = cap; ROWS = rows;
                rec_u2  = (size_t)NB * cap;
                spart_f = (size_t)rows * STRESS_FLOATS;
                break;
            }
        }
    }

    if (nchunks > 0) {
        uint2* rec   = (uint2*)d_ws;
        float* spart = (float*)(rec + rec_u2);
        int*   cnt   = (int*)(spart + spart_f);               // [nc][NB]
        float* stmp  = (float*)(cnt + (size_t)nchunks * NB);  // [64][1152]
        float* part  = stmp + (size_t)RS_SLICES * STRESS_FLOATS; // [S][NPAD*3]

        // only cnt needs zeroing (spart/stmp/partial fully overwritten)
        zero_i32_kernel<<<(nchunks * NB + BLK - 1) / BLK, BLK, 0, stream>>>(
            cnt, nchunks * NB);

        const int CH = (E + nchunks - 1) / nchunks;
        int chunk = 0;
        for (int s = 0; s < E; s += CH, ++chunk) {
            const int ce = min(CH, E - s);
            const int nb = (ce + EPB - 1) / EPB;

            scatter_kernel<<<nb, BLK_S, 0, stream>>>(
                dEdRij, Rij, idx_i, idx_j, idx_m,
                rec, cnt + (size_t)chunk * NB, spart, s, ce, CAP,
                chunk == 0 ? 1 : 0);

            accum_kernel<<<NB * SEG, BLK, 0, stream>>>(
                rec, cnt + (size_t)chunk * NB, part, CAP, SEG,
                chunk == 0 ? 1 : 0);
        }

        final_forces_kernel<<<(n3 + BLK - 1) / BLK, BLK, 0, stream>>>(
            part, forces, n3, SEG);
        reduce_stress_stage1<<<(STRESS_FLOATS * RS_SLICES + BLK - 1) / BLK,
                               BLK, 0, stream>>>(spart, stmp, ROWS);
        reduce_stress_stage2<<<(STRESS_FLOATS + BLK - 1) / BLK, BLK, 0, stream>>>(
            stmp, cell, stress_out);
    } else {
        // fallback: measured f64 atomic path
        double* facc   = (double*)d_ws;
        float*  spartf = (float*)(facc + n3);

        zero_f64_kernel<<<(n3 + BLK - 1) / BLK, BLK, 0, stream>>>(facc, n3);
        edge_kernel_f64<<<2048, BLK, 0, stream>>>(
            dEdRij, Rij, idx_i, idx_j, idx_m, facc, spartf, E);
        reduce_forces_f64_kernel<<<(n3 + BLK - 1) / BLK, BLK, 0, stream>>>(
            facc, forces, n3);
        reduce_stress_stage1<<<(STRESS_FLOATS * RS_SLICES + BLK - 1) / BLK,
                               BLK, 0, stream>>>(
            spartf, (float*)(spartf + (size_t)2048 * STRESS_FLOATS), 2048);
        reduce_stress_stage2<<<(STRESS_FLOATS + BLK - 1) / BLK, BLK, 0, stream>>>(
            (float*)(spartf + (size_t)2048 * STRESS_FLOATS), cell, stress_out);
    }
}